// Round 1
// baseline (1741.899 us; speedup 1.0000x reference)
//
#include <hip/hip_runtime.h>
#include <hip/hip_bf16.h>
#include <stdint.h>

#define T_TOK 8192
#define CDIM  1024
#define HDIM  4096
#define NEXP  8
#define TOPK_ 2

typedef __attribute__((ext_vector_type(8))) short short8;
typedef __attribute__((ext_vector_type(4))) float f32x4;

// ---------------- gate: logits -> softmax -> top2 -> row lists + aux partials ----------------
__global__ __launch_bounds__(256) void gate_kernel(
    const float* __restrict__ x, const float* __restrict__ gw,
    int* __restrict__ ecnt, int* __restrict__ erows,
    float* __restrict__ ew, float* __restrict__ spart)
{
  const int wid = threadIdx.x >> 6, lane = threadIdx.x & 63;
  const int t = blockIdx.x * 4 + wid;
  float acc[NEXP];
#pragma unroll
  for (int e = 0; e < NEXP; ++e) acc[e] = 0.f;
  const float* xr = x + (size_t)t * CDIM;
#pragma unroll
  for (int i = 0; i < CDIM / 64; ++i) {
    const float xv = xr[lane + 64 * i];
#pragma unroll
    for (int e = 0; e < NEXP; ++e) acc[e] += xv * gw[e * CDIM + lane + 64 * i];
  }
#pragma unroll
  for (int off = 32; off > 0; off >>= 1) {
#pragma unroll
    for (int e = 0; e < NEXP; ++e) acc[e] += __shfl_xor(acc[e], off);
  }
  float mx = acc[0];
#pragma unroll
  for (int e = 1; e < NEXP; ++e) mx = fmaxf(mx, acc[e]);
  float p[NEXP]; float s = 0.f;
#pragma unroll
  for (int e = 0; e < NEXP; ++e) { p[e] = __expf(acc[e] - mx); s += p[e]; }
  const float inv = 1.f / s;
#pragma unroll
  for (int e = 0; e < NEXP; ++e) p[e] *= inv;
  // top-2, strict > so ties pick the lower index (matches lax.top_k)
  float v0 = p[0]; int i0 = 0;
#pragma unroll
  for (int e = 1; e < NEXP; ++e) if (p[e] > v0) { v0 = p[e]; i0 = e; }
  float v1 = -1.f; int i1 = 0;
#pragma unroll
  for (int e = 0; e < NEXP; ++e) if (e != i0 && p[e] > v1) { v1 = p[e]; i1 = e; }

  __shared__ float sp[4][NEXP];
  if (lane == 0) {
#pragma unroll
    for (int e = 0; e < NEXP; ++e) sp[wid][e] = p[e];
    const float wn = 1.f / (v0 + v1);
    const int pos0 = atomicAdd(&ecnt[i0], 1);
    erows[i0 * T_TOK + pos0] = t; ew[i0 * T_TOK + pos0] = v0 * wn;
    const int pos1 = atomicAdd(&ecnt[i1], 1);
    erows[i1 * T_TOK + pos1] = t; ew[i1 * T_TOK + pos1] = v1 * wn;
  }
  __syncthreads();
  if (threadIdx.x < NEXP)
    spart[blockIdx.x * NEXP + threadIdx.x] =
        sp[0][threadIdx.x] + sp[1][threadIdx.x] + sp[2][threadIdx.x] + sp[3][threadIdx.x];
}

__global__ void finalize_kernel(const int* __restrict__ ecnt,
                                const float* __restrict__ spart,
                                float* __restrict__ aux_out)
{
  __shared__ float pis[NEXP];
  const int e = threadIdx.x;
  if (e < NEXP) {
    float s = 0.f;
    for (int b = 0; b < T_TOK / 4; ++b) s += spart[b * NEXP + e];
    pis[e] = s;
  }
  __syncthreads();
  if (threadIdx.x == 0) {
    float aux = 0.f;
    for (int k = 0; k < NEXP; ++k) {
      const float Pi = pis[k] / (float)T_TOK;
      const float ce = (float)ecnt[k] / (float)(T_TOK * TOPK_);
      aux += Pi * ce * (float)NEXP;
    }
    aux_out[0] = aux * 0.01f;
  }
}

// ---------------- x fp32 -> bf16 ----------------
__global__ __launch_bounds__(256) void cvt_x_kernel(const float* __restrict__ x,
                                                    __hip_bfloat16* __restrict__ xb)
{
  const int i = blockIdx.x * 256 + threadIdx.x;  // over T*C/4
  const float4 v = ((const float4*)x)[i];
  union { __hip_bfloat16 h[4]; uint2 u; } o;
  o.h[0] = __float2bfloat16(v.x); o.h[1] = __float2bfloat16(v.y);
  o.h[2] = __float2bfloat16(v.z); o.h[3] = __float2bfloat16(v.w);
  ((uint2*)xb)[i] = o.u;
}

// ---------------- transpose + convert: out[n*M+m] = bf16(in[m*N+n]) ----------------
__global__ __launch_bounds__(256) void transpose_cvt_kernel(
    const float* __restrict__ in, __hip_bfloat16* __restrict__ out, int M, int N)
{
  __shared__ float tile[32][33];
  const int tx = threadIdx.x & 31, ty = threadIdx.x >> 5;
  const int m0 = blockIdx.y * 32, n0 = blockIdx.x * 32;
#pragma unroll
  for (int i = 0; i < 4; ++i)
    tile[ty + 8 * i][tx] = in[(size_t)(m0 + ty + 8 * i) * N + n0 + tx];
  __syncthreads();
#pragma unroll
  for (int i = 0; i < 4; ++i)
    out[(size_t)(n0 + ty + 8 * i) * M + m0 + tx] = __float2bfloat16(tile[tx][ty + 8 * i]);
}

// ---------------- GEMM1: mid = silu(A@Wg^T) * (A@Wu^T); A rows gathered ----------------
// A: xb [T][C] bf16 (rows via rowlist); Bg/Bu: [H][C] bf16 (B^T layout). 128x128 tile, 4 waves.
template <bool GATHER>
__global__ __launch_bounds__(256, 2) void gemm1_kernel(
    const __hip_bfloat16* __restrict__ xb, const __hip_bfloat16* __restrict__ bgT,
    const __hip_bfloat16* __restrict__ buT, __hip_bfloat16* __restrict__ mid,
    const int* __restrict__ rowlist, const int* __restrict__ cnt_ptr, int row_base)
{
  __shared__ __align__(16) short lA[128 * 32];
  __shared__ __align__(16) short lBg[128 * 32];
  __shared__ __align__(16) short lBu[128 * 32];

  const int cnt = GATHER ? cnt_ptr[0] : T_TOK;
  const int rows_valid = cnt - row_base;
  if ((int)blockIdx.y * 128 >= rows_valid) return;

  const int tid = threadIdx.x, lane = tid & 63, w = tid >> 6;
  const int wr = w >> 1, wc = w & 1;
  const int r0 = tid >> 2, r1 = 64 + (tid >> 2);
  const int cb = (tid & 3) * 8;

  int ga0, ga1;
  if (GATHER) {
    const int l0 = row_base + (int)blockIdx.y * 128 + r0;
    const int l1 = row_base + (int)blockIdx.y * 128 + r1;
    ga0 = (l0 < cnt) ? rowlist[l0] : 0;
    ga1 = (l1 < cnt) ? rowlist[l1] : 0;
  } else {
    ga0 = row_base + (int)blockIdx.y * 128 + r0;
    ga1 = row_base + (int)blockIdx.y * 128 + r1;
  }
  const short* sA0 = (const short*)xb + (size_t)ga0 * CDIM + cb;
  const short* sA1 = (const short*)xb + (size_t)ga1 * CDIM + cb;
  const int n0 = blockIdx.x * 128;
  const short* sG0 = (const short*)bgT + (size_t)(n0 + r0) * CDIM + cb;
  const short* sG1 = (const short*)bgT + (size_t)(n0 + r1) * CDIM + cb;
  const short* sU0 = (const short*)buT + (size_t)(n0 + r0) * CDIM + cb;
  const short* sU1 = (const short*)buT + (size_t)(n0 + r1) * CDIM + cb;
  const int d0 = r0 * 32 + cb, d1 = r1 * 32 + cb;

  const int aoff = (wr * 64 + (lane & 15)) * 32 + (lane >> 4) * 8;
  const int boff = (wc * 64 + (lane & 15)) * 32 + (lane >> 4) * 8;

  f32x4 accg[4][4], accu[4][4];
#pragma unroll
  for (int i = 0; i < 4; ++i)
#pragma unroll
    for (int j = 0; j < 4; ++j) { accg[i][j] = (f32x4){0.f,0.f,0.f,0.f}; accu[i][j] = (f32x4){0.f,0.f,0.f,0.f}; }

  for (int k0 = 0; k0 < CDIM; k0 += 32) {
    const short8 va0 = *(const short8*)sA0; const short8 va1 = *(const short8*)sA1;
    const short8 vg0 = *(const short8*)sG0; const short8 vg1 = *(const short8*)sG1;
    const short8 vu0 = *(const short8*)sU0; const short8 vu1 = *(const short8*)sU1;
    sA0 += 32; sA1 += 32; sG0 += 32; sG1 += 32; sU0 += 32; sU1 += 32;
    __syncthreads();
    *(short8*)(lA + d0) = va0;  *(short8*)(lA + d1) = va1;
    *(short8*)(lBg + d0) = vg0; *(short8*)(lBg + d1) = vg1;
    *(short8*)(lBu + d0) = vu0; *(short8*)(lBu + d1) = vu1;
    __syncthreads();
    short8 af[4], gf[4], uf[4];
#pragma unroll
    for (int i = 0; i < 4; ++i) {
      af[i] = *(const short8*)(lA + aoff + i * 16 * 32);
      gf[i] = *(const short8*)(lBg + boff + i * 16 * 32);
      uf[i] = *(const short8*)(lBu + boff + i * 16 * 32);
    }
#pragma unroll
    for (int mi = 0; mi < 4; ++mi)
#pragma unroll
      for (int ni = 0; ni < 4; ++ni) {
        accg[mi][ni] = __builtin_amdgcn_mfma_f32_16x16x32_bf16(af[mi], gf[ni], accg[mi][ni], 0, 0, 0);
        accu[mi][ni] = __builtin_amdgcn_mfma_f32_16x16x32_bf16(af[mi], uf[ni], accu[mi][ni], 0, 0, 0);
      }
  }

  const int rb0 = (int)blockIdx.y * 128 + wr * 64;
  const int hb0 = n0 + wc * 64;
  const int rl = (lane >> 4) * 4, cl = lane & 15;
#pragma unroll
  for (int mi = 0; mi < 4; ++mi) {
#pragma unroll
    for (int j = 0; j < 4; ++j) {
      const int r = rb0 + mi * 16 + rl + j;
      if (r < rows_valid) {
        __hip_bfloat16* mp = mid + (size_t)r * HDIM + hb0 + cl;
#pragma unroll
        for (int ni = 0; ni < 4; ++ni) {
          const float g = accg[mi][ni][j], u = accu[mi][ni][j];
          const float sv = g / (1.f + __expf(-g));
          mp[ni * 16] = __float2bfloat16(sv * u);
        }
      }
    }
  }
}

// ---------------- GEMM2: y(+)= weight * (mid @ Wd) ----------------
// A: mid [RC][H] bf16; B: wdT [C][H] bf16 (B^T layout). GATHER: atomicAdd with per-row weight.
template <bool GATHER>
__global__ __launch_bounds__(256, 2) void gemm2_kernel(
    const __hip_bfloat16* __restrict__ mid, const __hip_bfloat16* __restrict__ bdT,
    float* __restrict__ y, const int* __restrict__ rowlist,
    const float* __restrict__ roww, const int* __restrict__ cnt_ptr,
    int row_base, const float* __restrict__ sscale)
{
  __shared__ __align__(16) short lA[128 * 32];
  __shared__ __align__(16) short lB[128 * 32];

  const int cnt = GATHER ? cnt_ptr[0] : T_TOK;
  const int rows_valid = cnt - row_base;
  if ((int)blockIdx.y * 128 >= rows_valid) return;

  const int tid = threadIdx.x, lane = tid & 63, w = tid >> 6;
  const int wr = w >> 1, wc = w & 1;
  const int r0 = tid >> 2, r1 = 64 + (tid >> 2);
  const int cb = (tid & 3) * 8;

  const short* sA0 = (const short*)mid + (size_t)((int)blockIdx.y * 128 + r0) * HDIM + cb;
  const short* sA1 = (const short*)mid + (size_t)((int)blockIdx.y * 128 + r1) * HDIM + cb;
  const int n0 = blockIdx.x * 128;
  const short* sB0 = (const short*)bdT + (size_t)(n0 + r0) * HDIM + cb;
  const short* sB1 = (const short*)bdT + (size_t)(n0 + r1) * HDIM + cb;
  const int d0 = r0 * 32 + cb, d1 = r1 * 32 + cb;
  const int aoff = (wr * 64 + (lane & 15)) * 32 + (lane >> 4) * 8;
  const int boff = (wc * 64 + (lane & 15)) * 32 + (lane >> 4) * 8;

  f32x4 acc[4][4];
#pragma unroll
  for (int i = 0; i < 4; ++i)
#pragma unroll
    for (int j = 0; j < 4; ++j) acc[i][j] = (f32x4){0.f,0.f,0.f,0.f};

  for (int k0 = 0; k0 < HDIM; k0 += 32) {
    const short8 va0 = *(const short8*)sA0; const short8 va1 = *(const short8*)sA1;
    const short8 vb0 = *(const short8*)sB0; const short8 vb1 = *(const short8*)sB1;
    sA0 += 32; sA1 += 32; sB0 += 32; sB1 += 32;
    __syncthreads();
    *(short8*)(lA + d0) = va0; *(short8*)(lA + d1) = va1;
    *(short8*)(lB + d0) = vb0; *(short8*)(lB + d1) = vb1;
    __syncthreads();
    short8 af[4], bf[4];
#pragma unroll
    for (int i = 0; i < 4; ++i) {
      af[i] = *(const short8*)(lA + aoff + i * 16 * 32);
      bf[i] = *(const short8*)(lB + boff + i * 16 * 32);
    }
#pragma unroll
    for (int mi = 0; mi < 4; ++mi)
#pragma unroll
      for (int ni = 0; ni < 4; ++ni)
        acc[mi][ni] = __builtin_amdgcn_mfma_f32_16x16x32_bf16(af[mi], bf[ni], acc[mi][ni], 0, 0, 0);
  }

  const int rb0 = (int)blockIdx.y * 128 + wr * 64;
  const int cb0 = n0 + wc * 64;
  const int rl = (lane >> 4) * 4, cl = lane & 15;
#pragma unroll
  for (int mi = 0; mi < 4; ++mi) {
#pragma unroll
    for (int j = 0; j < 4; ++j) {
      const int r = rb0 + mi * 16 + rl + j;
      if (r < rows_valid) {
        const int lrow = row_base + r;
        if (GATHER) {
          const int tok = rowlist[lrow];
          const float wgt = roww[lrow];
          float* yp = y + (size_t)tok * CDIM + cb0 + cl;
#pragma unroll
          for (int ni = 0; ni < 4; ++ni) unsafeAtomicAdd(yp + ni * 16, wgt * acc[mi][ni][j]);
        } else {
          const float ss = sscale[0];
          float* yp = y + (size_t)lrow * CDIM + cb0 + cl;
#pragma unroll
          for (int ni = 0; ni < 4; ++ni) yp[ni * 16] = ss * acc[mi][ni][j];
        }
      }
    }
  }
}

// ---------------- host ----------------
extern "C" void kernel_launch(void* const* d_in, const int* in_sizes, int n_in,
                              void* d_out, int out_size, void* d_ws, size_t ws_size,
                              hipStream_t stream)
{
  const float* x   = (const float*)d_in[0];
  const float* gw  = (const float*)d_in[1];
  const float* wg  = (const float*)d_in[2];
  const float* wu  = (const float*)d_in[3];
  const float* wd  = (const float*)d_in[4];
  const float* swg = (const float*)d_in[5];
  const float* swu = (const float*)d_in[6];
  const float* swd = (const float*)d_in[7];
  const float* ssc = (const float*)d_in[8];
  float* y = (float*)d_out;

  char* ws = (char*)d_ws;
  size_t off = 0;
  __hip_bfloat16* xb  = (__hip_bfloat16*)(ws + off); off += (size_t)T_TOK * CDIM * 2;
  __hip_bfloat16* wgT = (__hip_bfloat16*)(ws + off); off += (size_t)HDIM * CDIM * 2;
  __hip_bfloat16* wuT = (__hip_bfloat16*)(ws + off); off += (size_t)HDIM * CDIM * 2;
  __hip_bfloat16* wdT = (__hip_bfloat16*)(ws + off); off += (size_t)CDIM * HDIM * 2;
  int*   ecnt  = (int*)(ws + off);   off += 256;
  int*   erows = (int*)(ws + off);   off += (size_t)NEXP * T_TOK * 4;
  float* ew    = (float*)(ws + off); off += (size_t)NEXP * T_TOK * 4;
  float* spart = (float*)(ws + off); off += (size_t)(T_TOK / 4) * NEXP * 4;
  off = (off + 255) & ~(size_t)255;
  __hip_bfloat16* mid = (__hip_bfloat16*)(ws + off);
  const size_t mid_avail = (ws_size > off) ? (ws_size - off) : 0;
  int RC = 1024;
  if      (mid_avail >= (size_t)8192 * HDIM * 2) RC = 8192;
  else if (mid_avail >= (size_t)4096 * HDIM * 2) RC = 4096;
  else if (mid_avail >= (size_t)2048 * HDIM * 2) RC = 2048;

  hipMemsetAsync(ecnt, 0, NEXP * sizeof(int), stream);
  gate_kernel<<<T_TOK / 4, 256, 0, stream>>>(x, gw, ecnt, erows, ew, spart);
  finalize_kernel<<<1, 64, 0, stream>>>(ecnt, spart, y + (size_t)T_TOK * CDIM);
  cvt_x_kernel<<<T_TOK * CDIM / 4 / 256, 256, 0, stream>>>(x, xb);

  // shared expert first: plain stores establish y (handles poisoned d_out), routed adds after.
  transpose_cvt_kernel<<<dim3(HDIM / 32, CDIM / 32), 256, 0, stream>>>(swg, wgT, CDIM, HDIM);
  transpose_cvt_kernel<<<dim3(HDIM / 32, CDIM / 32), 256, 0, stream>>>(swu, wuT, CDIM, HDIM);
  transpose_cvt_kernel<<<dim3(CDIM / 32, HDIM / 32), 256, 0, stream>>>(swd, wdT, HDIM, CDIM);
  for (int rb = 0; rb < T_TOK; rb += RC) {
    gemm1_kernel<false><<<dim3(HDIM / 128, RC / 128), 256, 0, stream>>>(
        xb, wgT, wuT, mid, nullptr, nullptr, rb);
    gemm2_kernel<false><<<dim3(CDIM / 128, RC / 128), 256, 0, stream>>>(
        mid, wdT, y, nullptr, nullptr, nullptr, rb, ssc);
  }
  for (int e = 0; e < NEXP; ++e) {
    transpose_cvt_kernel<<<dim3(HDIM / 32, CDIM / 32), 256, 0, stream>>>(
        wg + (size_t)e * CDIM * HDIM, wgT, CDIM, HDIM);
    transpose_cvt_kernel<<<dim3(HDIM / 32, CDIM / 32), 256, 0, stream>>>(
        wu + (size_t)e * CDIM * HDIM, wuT, CDIM, HDIM);
    transpose_cvt_kernel<<<dim3(CDIM / 32, HDIM / 32), 256, 0, stream>>>(
        wd + (size_t)e * HDIM * CDIM, wdT, HDIM, CDIM);
    for (int rb = 0; rb < T_TOK; rb += RC) {
      gemm1_kernel<true><<<dim3(HDIM / 128, RC / 128), 256, 0, stream>>>(
          xb, wgT, wuT, mid, erows + (size_t)e * T_TOK, ecnt + e, rb);
      gemm2_kernel<true><<<dim3(CDIM / 128, RC / 128), 256, 0, stream>>>(
          mid, wdT, y, erows + (size_t)e * T_TOK, ew + (size_t)e * T_TOK, ecnt + e, rb, nullptr);
    }
  }
}

// Round 2
// 1556.822 us; speedup vs baseline: 1.1189x; 1.1189x over previous
//
#include <hip/hip_runtime.h>
#include <hip/hip_bf16.h>
#include <stdint.h>

#define T_TOK 8192
#define CDIM  1024
#define HDIM  4096
#define NEXP  8
#define TOPK_ 2

typedef __attribute__((ext_vector_type(8))) short short8;
typedef __attribute__((ext_vector_type(4))) float f32x4;

__device__ __forceinline__ void gload16(const short* g, short* l) {
  __builtin_amdgcn_global_load_lds(
      (const __attribute__((address_space(1))) unsigned int*)(g),
      (__attribute__((address_space(3))) unsigned int*)(l), 16, 0, 0);
}

// ---------------- gate phase A: softmax/top2 per token, per-block histogram ----------------
__global__ __launch_bounds__(256) void gate_kernel(
    const float* __restrict__ x, const float* __restrict__ gw,
    int* __restrict__ tokinfo, float* __restrict__ tokw,
    int* __restrict__ bcnt, float* __restrict__ spart)
{
  const int wid = threadIdx.x >> 6, lane = threadIdx.x & 63;
  const int t = blockIdx.x * 4 + wid;
  float acc[NEXP];
#pragma unroll
  for (int e = 0; e < NEXP; ++e) acc[e] = 0.f;
  const float4* xr = (const float4*)x + (size_t)t * (CDIM / 4);
  const float4* gw4 = (const float4*)gw;
#pragma unroll
  for (int i = 0; i < CDIM / 256; ++i) {
    const float4 xv = xr[lane + 64 * i];
#pragma unroll
    for (int e = 0; e < NEXP; ++e) {
      const float4 gv = gw4[e * (CDIM / 4) + lane + 64 * i];
      acc[e] += xv.x * gv.x + xv.y * gv.y + xv.z * gv.z + xv.w * gv.w;
    }
  }
#pragma unroll
  for (int off = 32; off > 0; off >>= 1) {
#pragma unroll
    for (int e = 0; e < NEXP; ++e) acc[e] += __shfl_xor(acc[e], off);
  }
  float mx = acc[0];
#pragma unroll
  for (int e = 1; e < NEXP; ++e) mx = fmaxf(mx, acc[e]);
  float p[NEXP]; float s = 0.f;
#pragma unroll
  for (int e = 0; e < NEXP; ++e) { p[e] = __expf(acc[e] - mx); s += p[e]; }
  const float inv = 1.f / s;
#pragma unroll
  for (int e = 0; e < NEXP; ++e) p[e] *= inv;
  // top-2, strict > so ties pick the lower index (matches lax.top_k)
  float v0 = p[0]; int i0 = 0;
#pragma unroll
  for (int e = 1; e < NEXP; ++e) if (p[e] > v0) { v0 = p[e]; i0 = e; }
  float v1 = -1.f; int i1 = 0;
#pragma unroll
  for (int e = 0; e < NEXP; ++e) if (e != i0 && p[e] > v1) { v1 = p[e]; i1 = e; }

  __shared__ float sp[4][NEXP];
  __shared__ int   se[4][2];
  __shared__ float swt[4][2];
  if (lane == 0) {
#pragma unroll
    for (int e = 0; e < NEXP; ++e) sp[wid][e] = p[e];
    const float wn = 1.f / (v0 + v1);
    se[wid][0] = i0; se[wid][1] = i1;
    swt[wid][0] = v0 * wn; swt[wid][1] = v1 * wn;
  }
  __syncthreads();
  if (threadIdx.x == 0) {
    int cnt[NEXP];
#pragma unroll
    for (int e = 0; e < NEXP; ++e) cnt[e] = 0;
#pragma unroll
    for (int tt = 0; tt < 4; ++tt) {
      const int e0 = se[tt][0], e1 = se[tt][1];
      const int r0 = cnt[e0]++; const int r1 = cnt[e1]++;
      tokinfo[blockIdx.x * 4 + tt] = e0 | (e1 << 3) | (r0 << 6) | (r1 << 10);
      ((float2*)tokw)[blockIdx.x * 4 + tt] = make_float2(swt[tt][0], swt[tt][1]);
    }
#pragma unroll
    for (int e = 0; e < NEXP; ++e) bcnt[blockIdx.x * NEXP + e] = cnt[e];
  }
  if (threadIdx.x < NEXP)
    spart[blockIdx.x * NEXP + threadIdx.x] =
        sp[0][threadIdx.x] + sp[1][threadIdx.x] + sp[2][threadIdx.x] + sp[3][threadIdx.x];
}

// ---------------- gate phase B: scan block counts -> offsets, ecnt, aux loss ----------------
__global__ __launch_bounds__(512) void scan_kernel(
    const int* __restrict__ bcnt, int* __restrict__ boff, int* __restrict__ ecnt,
    const float* __restrict__ spart, float* __restrict__ aux_out)
{
  const int w = threadIdx.x >> 6, l = threadIdx.x & 63;  // wave w handles expert w
  int run = 0;
#pragma unroll 4
  for (int c = 0; c < (T_TOK / 4) / 64; ++c) {
    const int b = c * 64 + l;
    const int v = bcnt[b * NEXP + w];
    int sc = v;
#pragma unroll
    for (int off = 1; off < 64; off <<= 1) {
      const int t = __shfl_up(sc, off);
      if (l >= off) sc += t;
    }
    boff[b * NEXP + w] = run + sc - v;
    run += __shfl(sc, 63);
  }
  if (l == 0) ecnt[w] = run;
  float fs = 0.f;
  for (int c = 0; c < (T_TOK / 4) / 64; ++c) fs += spart[(c * 64 + l) * NEXP + w];
#pragma unroll
  for (int off = 32; off > 0; off >>= 1) fs += __shfl_xor(fs, off);
  __shared__ float pis[NEXP];
  __shared__ int cs[NEXP];
  if (l == 0) { pis[w] = fs; cs[w] = run; }
  __syncthreads();
  if (threadIdx.x == 0) {
    float aux = 0.f;
#pragma unroll
    for (int e = 0; e < NEXP; ++e) {
      const float Pi = pis[e] / (float)T_TOK;
      const float ce = (float)cs[e] / (float)(T_TOK * TOPK_);
      aux += Pi * ce * (float)NEXP;
    }
    aux_out[0] = aux * 0.01f;
  }
}

// ---------------- gate phase C: scatter tokens into per-expert row lists ----------------
__global__ __launch_bounds__(256) void scatter_kernel(
    const int* __restrict__ tokinfo, const float* __restrict__ tokw,
    const int* __restrict__ boff, int* __restrict__ erows, float* __restrict__ ew)
{
  const int t = blockIdx.x * 256 + threadIdx.x;
  const int info = tokinfo[t];
  const int e0 = info & 7, e1 = (info >> 3) & 7;
  const int r0 = (info >> 6) & 15, r1 = (info >> 10) & 15;
  const int b = t >> 2;
  const float2 wv = ((const float2*)tokw)[t];
  const int p0 = boff[b * NEXP + e0] + r0;
  erows[e0 * T_TOK + p0] = t; ew[e0 * T_TOK + p0] = wv.x;
  const int p1 = boff[b * NEXP + e1] + r1;
  erows[e1 * T_TOK + p1] = t; ew[e1 * T_TOK + p1] = wv.y;
}

// ---------------- x fp32 -> bf16 ----------------
__global__ __launch_bounds__(256) void cvt_x_kernel(const float* __restrict__ x,
                                                    __hip_bfloat16* __restrict__ xb)
{
  const int i = blockIdx.x * 256 + threadIdx.x;  // over T*C/4
  const float4 v = ((const float4*)x)[i];
  union { __hip_bfloat16 h[4]; uint2 u; } o;
  o.h[0] = __float2bfloat16(v.x); o.h[1] = __float2bfloat16(v.y);
  o.h[2] = __float2bfloat16(v.z); o.h[3] = __float2bfloat16(v.w);
  ((uint2*)xb)[i] = o.u;
}

// ---------------- transpose + convert: out[n*M+m] = bf16(in[m*N+n]) ----------------
__global__ __launch_bounds__(256) void transpose_cvt_kernel(
    const float* __restrict__ in, __hip_bfloat16* __restrict__ out, int M, int N)
{
  __shared__ float tile[32][33];
  const int tx = threadIdx.x & 31, ty = threadIdx.x >> 5;
  const int m0 = blockIdx.y * 32, n0 = blockIdx.x * 32;
#pragma unroll
  for (int i = 0; i < 4; ++i)
    tile[ty + 8 * i][tx] = in[(size_t)(m0 + ty + 8 * i) * N + n0 + tx];
  __syncthreads();
#pragma unroll
  for (int i = 0; i < 4; ++i)
    out[(size_t)(n0 + ty + 8 * i) * M + m0 + tx] = __float2bfloat16(tile[tx][ty + 8 * i]);
}

// ---------------- GEMM1: mid = silu(A@Wg^T) * (A@Wu^T); m97-style global_load_lds staging ----
template <bool GATHER>
__global__ __launch_bounds__(256, 2) void gemm1_kernel(
    const __hip_bfloat16* __restrict__ xb, const __hip_bfloat16* __restrict__ bgT,
    const __hip_bfloat16* __restrict__ buT, __hip_bfloat16* __restrict__ mid,
    const int* __restrict__ rowlist, const int* __restrict__ cnt_ptr, int row_base)
{
  __shared__ __align__(16) short lA[128 * 32];
  __shared__ __align__(16) short lBg[128 * 32];
  __shared__ __align__(16) short lBu[128 * 32];

  const int cnt = GATHER ? cnt_ptr[0] : T_TOK;
  const int rows_valid = cnt - row_base;
  if ((int)blockIdx.y * 128 >= rows_valid) return;

  const int tid = threadIdx.x, lane = tid & 63, w = tid >> 6;
  const int wr = w >> 1, wc = w & 1;
  // staging geometry: phase p base elem (w+4p)*512; lane l -> row (w+4p)*16 + (l>>2), k8=(l&3)*8
  const int rs0 = w * 16 + (lane >> 2);
  const int rs1 = rs0 + 64;
  const int k8 = (lane & 3) * 8;

  int ga0, ga1;
  if (GATHER) {
    const int l0 = row_base + (int)blockIdx.y * 128 + rs0;
    const int l1 = row_base + (int)blockIdx.y * 128 + rs1;
    ga0 = (l0 < cnt) ? rowlist[l0] : 0;
    ga1 = (l1 < cnt) ? rowlist[l1] : 0;
  } else {
    ga0 = row_base + (int)blockIdx.y * 128 + rs0;
    ga1 = row_base + (int)blockIdx.y * 128 + rs1;
  }
  const short* sA0 = (const short*)xb + (size_t)ga0 * CDIM + k8;
  const short* sA1 = (const short*)xb + (size_t)ga1 * CDIM + k8;
  const int n0 = blockIdx.x * 128;
  const short* sG0 = (const short*)bgT + (size_t)(n0 + rs0) * CDIM + k8;
  const short* sG1 = (const short*)bgT + (size_t)(n0 + rs1) * CDIM + k8;
  const short* sU0 = (const short*)buT + (size_t)(n0 + rs0) * CDIM + k8;
  const short* sU1 = (const short*)buT + (size_t)(n0 + rs1) * CDIM + k8;
  short* dA0 = lA + w * 512;  short* dA1 = dA0 + 2048;
  short* dG0 = lBg + w * 512; short* dG1 = dG0 + 2048;
  short* dU0 = lBu + w * 512; short* dU1 = dU0 + 2048;

  const int aoff = (wr * 64 + (lane & 15)) * 32 + (lane >> 4) * 8;
  const int boff = (wc * 64 + (lane & 15)) * 32 + (lane >> 4) * 8;

  f32x4 accg[4][4], accu[4][4];
#pragma unroll
  for (int i = 0; i < 4; ++i)
#pragma unroll
    for (int j = 0; j < 4; ++j) { accg[i][j] = (f32x4){0.f,0.f,0.f,0.f}; accu[i][j] = (f32x4){0.f,0.f,0.f,0.f}; }

  for (int k0 = 0; k0 < CDIM; k0 += 32) {
    gload16(sA0, dA0); gload16(sA1, dA1);
    gload16(sG0, dG0); gload16(sG1, dG1);
    gload16(sU0, dU0); gload16(sU1, dU1);
    sA0 += 32; sA1 += 32; sG0 += 32; sG1 += 32; sU0 += 32; sU1 += 32;
    __syncthreads();
    short8 af[4], gf[4], uf[4];
#pragma unroll
    for (int i = 0; i < 4; ++i) {
      af[i] = *(const short8*)(lA + aoff + i * 16 * 32);
      gf[i] = *(const short8*)(lBg + boff + i * 16 * 32);
      uf[i] = *(const short8*)(lBu + boff + i * 16 * 32);
    }
#pragma unroll
    for (int mi = 0; mi < 4; ++mi)
#pragma unroll
      for (int ni = 0; ni < 4; ++ni) {
        accg[mi][ni] = __builtin_amdgcn_mfma_f32_16x16x32_bf16(af[mi], gf[ni], accg[mi][ni], 0, 0, 0);
        accu[mi][ni] = __builtin_amdgcn_mfma_f32_16x16x32_bf16(af[mi], uf[ni], accu[mi][ni], 0, 0, 0);
      }
    __syncthreads();
  }

  const int rb0 = (int)blockIdx.y * 128 + wr * 64;
  const int hb0 = n0 + wc * 64;
  const int rl = (lane >> 4) * 4, cl = lane & 15;
#pragma unroll
  for (int mi = 0; mi < 4; ++mi) {
#pragma unroll
    for (int j = 0; j < 4; ++j) {
      const int r = rb0 + mi * 16 + rl + j;
      if (r < rows_valid) {
        __hip_bfloat16* mp = mid + (size_t)r * HDIM + hb0 + cl;
#pragma unroll
        for (int ni = 0; ni < 4; ++ni) {
          const float g = accg[mi][ni][j], u = accu[mi][ni][j];
          const float sv = g / (1.f + __expf(-g));
          mp[ni * 16] = __float2bfloat16(sv * u);
        }
      }
    }
  }
}

// ---------------- GEMM2: y(+)= weight * (mid @ Wd); m97-style staging ----------------
template <bool GATHER>
__global__ __launch_bounds__(256, 2) void gemm2_kernel(
    const __hip_bfloat16* __restrict__ mid, const __hip_bfloat16* __restrict__ bdT,
    float* __restrict__ y, const int* __restrict__ rowlist,
    const float* __restrict__ roww, const int* __restrict__ cnt_ptr,
    int row_base, const float* __restrict__ sscale)
{
  __shared__ __align__(16) short lA[128 * 32];
  __shared__ __align__(16) short lB[128 * 32];

  const int cnt = GATHER ? cnt_ptr[0] : T_TOK;
  const int rows_valid = cnt - row_base;
  if ((int)blockIdx.y * 128 >= rows_valid) return;

  const int tid = threadIdx.x, lane = tid & 63, w = tid >> 6;
  const int wr = w >> 1, wc = w & 1;
  const int rs0 = w * 16 + (lane >> 2);
  const int rs1 = rs0 + 64;
  const int k8 = (lane & 3) * 8;

  const short* sA0 = (const short*)mid + (size_t)((int)blockIdx.y * 128 + rs0) * HDIM + k8;
  const short* sA1 = (const short*)mid + (size_t)((int)blockIdx.y * 128 + rs1) * HDIM + k8;
  const int n0 = blockIdx.x * 128;
  const short* sB0 = (const short*)bdT + (size_t)(n0 + rs0) * HDIM + k8;
  const short* sB1 = (const short*)bdT + (size_t)(n0 + rs1) * HDIM + k8;
  short* dA0 = lA + w * 512; short* dA1 = dA0 + 2048;
  short* dB0 = lB + w * 512; short* dB1 = dB0 + 2048;

  const int aoff = (wr * 64 + (lane & 15)) * 32 + (lane >> 4) * 8;
  const int boff = (wc * 64 + (lane & 15)) * 32 + (lane >> 4) * 8;

  f32x4 acc[4][4];
#pragma unroll
  for (int i = 0; i < 4; ++i)
#pragma unroll
    for (int j = 0; j < 4; ++j) acc[i][j] = (f32x4){0.f,0.f,0.f,0.f};

  for (int k0 = 0; k0 < HDIM; k0 += 32) {
    gload16(sA0, dA0); gload16(sA1, dA1);
    gload16(sB0, dB0); gload16(sB1, dB1);
    sA0 += 32; sA1 += 32; sB0 += 32; sB1 += 32;
    __syncthreads();
    short8 af[4], bf[4];
#pragma unroll
    for (int i = 0; i < 4; ++i) {
      af[i] = *(const short8*)(lA + aoff + i * 16 * 32);
      bf[i] = *(const short8*)(lB + boff + i * 16 * 32);
    }
#pragma unroll
    for (int mi = 0; mi < 4; ++mi)
#pragma unroll
      for (int ni = 0; ni < 4; ++ni)
        acc[mi][ni] = __builtin_amdgcn_mfma_f32_16x16x32_bf16(af[mi], bf[ni], acc[mi][ni], 0, 0, 0);
    __syncthreads();
  }

  const int rb0 = (int)blockIdx.y * 128 + wr * 64;
  const int cb0 = n0 + wc * 64;
  const int rl = (lane >> 4) * 4, cl = lane & 15;
#pragma unroll
  for (int mi = 0; mi < 4; ++mi) {
#pragma unroll
    for (int j = 0; j < 4; ++j) {
      const int r = rb0 + mi * 16 + rl + j;
      if (r < rows_valid) {
        const int lrow = row_base + r;
        if (GATHER) {
          const int tok = rowlist[lrow];
          const float wgt = roww[lrow];
          float* yp = y + (size_t)tok * CDIM + cb0 + cl;
#pragma unroll
        for (int ni = 0; ni < 4; ++ni) unsafeAtomicAdd(yp + ni * 16, wgt * acc[mi][ni][j]);
        } else {
          const float ss = sscale[0];
          float* yp = y + (size_t)lrow * CDIM + cb0 + cl;
#pragma unroll
          for (int ni = 0; ni < 4; ++ni) yp[ni * 16] = ss * acc[mi][ni][j];
        }
      }
    }
  }
}

// ---------------- host ----------------
extern "C" void kernel_launch(void* const* d_in, const int* in_sizes, int n_in,
                              void* d_out, int out_size, void* d_ws, size_t ws_size,
                              hipStream_t stream)
{
  const float* x   = (const float*)d_in[0];
  const float* gw  = (const float*)d_in[1];
  const float* wg  = (const float*)d_in[2];
  const float* wu  = (const float*)d_in[3];
  const float* wd  = (const float*)d_in[4];
  const float* swg = (const float*)d_in[5];
  const float* swu = (const float*)d_in[6];
  const float* swd = (const float*)d_in[7];
  const float* ssc = (const float*)d_in[8];
  float* y = (float*)d_out;

  char* ws = (char*)d_ws;
  size_t off = 0;
  __hip_bfloat16* xb  = (__hip_bfloat16*)(ws + off); off += (size_t)T_TOK * CDIM * 2;
  __hip_bfloat16* wgT = (__hip_bfloat16*)(ws + off); off += (size_t)HDIM * CDIM * 2;
  __hip_bfloat16* wuT = (__hip_bfloat16*)(ws + off); off += (size_t)HDIM * CDIM * 2;
  __hip_bfloat16* wdT = (__hip_bfloat16*)(ws + off); off += (size_t)CDIM * HDIM * 2;
  int*   ecnt  = (int*)(ws + off);   off += 256;
  int*   erows = (int*)(ws + off);   off += (size_t)NEXP * T_TOK * 4;
  float* ew    = (float*)(ws + off); off += (size_t)NEXP * T_TOK * 4;
  int*   tokinfo = (int*)(ws + off); off += (size_t)T_TOK * 4;
  float* tokw  = (float*)(ws + off); off += (size_t)T_TOK * 8;
  int*   bcnt  = (int*)(ws + off);   off += (size_t)(T_TOK / 4) * NEXP * 4;
  int*   boff  = (int*)(ws + off);   off += (size_t)(T_TOK / 4) * NEXP * 4;
  float* spart = (float*)(ws + off); off += (size_t)(T_TOK / 4) * NEXP * 4;
  off = (off + 255) & ~(size_t)255;
  __hip_bfloat16* mid = (__hip_bfloat16*)(ws + off);
  const size_t mid_avail = (ws_size > off) ? (ws_size - off) : 0;
  int RC = 1024;
  if      (mid_avail >= (size_t)8192 * HDIM * 2) RC = 8192;
  else if (mid_avail >= (size_t)4096 * HDIM * 2) RC = 4096;
  else if (mid_avail >= (size_t)2048 * HDIM * 2) RC = 2048;

  gate_kernel<<<T_TOK / 4, 256, 0, stream>>>(x, gw, tokinfo, tokw, bcnt, spart);
  scan_kernel<<<1, 512, 0, stream>>>(bcnt, boff, ecnt, spart, y + (size_t)T_TOK * CDIM);
  scatter_kernel<<<T_TOK / 256, 256, 0, stream>>>(tokinfo, tokw, boff, erows, ew);
  cvt_x_kernel<<<T_TOK * CDIM / 4 / 256, 256, 0, stream>>>(x, xb);

  // shared expert first: plain stores establish y (handles poisoned d_out), routed adds after.
  transpose_cvt_kernel<<<dim3(HDIM / 32, CDIM / 32), 256, 0, stream>>>(swg, wgT, CDIM, HDIM);
  transpose_cvt_kernel<<<dim3(HDIM / 32, CDIM / 32), 256, 0, stream>>>(swu, wuT, CDIM, HDIM);
  transpose_cvt_kernel<<<dim3(CDIM / 32, HDIM / 32), 256, 0, stream>>>(swd, wdT, HDIM, CDIM);
  for (int rb = 0; rb < T_TOK; rb += RC) {
    gemm1_kernel<false><<<dim3(HDIM / 128, RC / 128), 256, 0, stream>>>(
        xb, wgT, wuT, mid, nullptr, nullptr, rb);
    gemm2_kernel<false><<<dim3(CDIM / 128, RC / 128), 256, 0, stream>>>(
        mid, wdT, y, nullptr, nullptr, nullptr, rb, ssc);
  }
  for (int e = 0; e < NEXP; ++e) {
    transpose_cvt_kernel<<<dim3(HDIM / 32, CDIM / 32), 256, 0, stream>>>(
        wg + (size_t)e * CDIM * HDIM, wgT, CDIM, HDIM);
    transpose_cvt_kernel<<<dim3(HDIM / 32, CDIM / 32), 256, 0, stream>>>(
        wu + (size_t)e * CDIM * HDIM, wuT, CDIM, HDIM);
    transpose_cvt_kernel<<<dim3(CDIM / 32, HDIM / 32), 256, 0, stream>>>(
        wd + (size_t)e * HDIM * CDIM, wdT, HDIM, CDIM);
    for (int rb = 0; rb < T_TOK; rb += RC) {
      gemm1_kernel<true><<<dim3(HDIM / 128, RC / 128), 256, 0, stream>>>(
          xb, wgT, wuT, mid, erows + (size_t)e * T_TOK, ecnt + e, rb);
      gemm2_kernel<true><<<dim3(CDIM / 128, RC / 128), 256, 0, stream>>>(
          mid, wdT, y, erows + (size_t)e * T_TOK, ew + (size_t)e * T_TOK, ecnt + e, rb, nullptr);
    }
  }
}

// Round 3
// 1062.703 us; speedup vs baseline: 1.6391x; 1.4650x over previous
//
#include <hip/hip_runtime.h>
#include <hip/hip_bf16.h>
#include <stdint.h>

#define T_TOK 8192
#define CDIM  1024
#define HDIM  4096
#define NEXP  8
#define TOPK_ 2
#define MAXTILES 136   // sum ceil(cnt_e/128) <= 128+7 = 135
#define MAXROWS  17280 // 135*128

typedef __attribute__((ext_vector_type(8))) short short8;
typedef __attribute__((ext_vector_type(4))) float f32x4;

__device__ __forceinline__ void gload16(const short* g, short* l) {
  __builtin_amdgcn_global_load_lds(
      (const __attribute__((address_space(1))) unsigned int*)(g),
      (__attribute__((address_space(3))) unsigned int*)(l), 16, 0, 0);
}

// ---------------- gate phase A: softmax/top2 per token, per-block histogram ----------------
__global__ __launch_bounds__(256) void gate_kernel(
    const float* __restrict__ x, const float* __restrict__ gw,
    int* __restrict__ tokinfo, float* __restrict__ tokw,
    int* __restrict__ bcnt, float* __restrict__ spart)
{
  const int wid = threadIdx.x >> 6, lane = threadIdx.x & 63;
  const int t = blockIdx.x * 4 + wid;
  float acc[NEXP];
#pragma unroll
  for (int e = 0; e < NEXP; ++e) acc[e] = 0.f;
  const float4* xr = (const float4*)x + (size_t)t * (CDIM / 4);
  const float4* gw4 = (const float4*)gw;
#pragma unroll
  for (int i = 0; i < CDIM / 256; ++i) {
    const float4 xv = xr[lane + 64 * i];
#pragma unroll
    for (int e = 0; e < NEXP; ++e) {
      const float4 gv = gw4[e * (CDIM / 4) + lane + 64 * i];
      acc[e] += xv.x * gv.x + xv.y * gv.y + xv.z * gv.z + xv.w * gv.w;
    }
  }
#pragma unroll
  for (int off = 32; off > 0; off >>= 1) {
#pragma unroll
    for (int e = 0; e < NEXP; ++e) acc[e] += __shfl_xor(acc[e], off);
  }
  float mx = acc[0];
#pragma unroll
  for (int e = 1; e < NEXP; ++e) mx = fmaxf(mx, acc[e]);
  float p[NEXP]; float s = 0.f;
#pragma unroll
  for (int e = 0; e < NEXP; ++e) { p[e] = __expf(acc[e] - mx); s += p[e]; }
  const float inv = 1.f / s;
#pragma unroll
  for (int e = 0; e < NEXP; ++e) p[e] *= inv;
  float v0 = p[0]; int i0 = 0;
#pragma unroll
  for (int e = 1; e < NEXP; ++e) if (p[e] > v0) { v0 = p[e]; i0 = e; }
  float v1 = -1.f; int i1 = 0;
#pragma unroll
  for (int e = 0; e < NEXP; ++e) if (e != i0 && p[e] > v1) { v1 = p[e]; i1 = e; }

  __shared__ float sp[4][NEXP];
  __shared__ int   se[4][2];
  __shared__ float swt[4][2];
  if (lane == 0) {
#pragma unroll
    for (int e = 0; e < NEXP; ++e) sp[wid][e] = p[e];
    const float wn = 1.f / (v0 + v1);
    se[wid][0] = i0; se[wid][1] = i1;
    swt[wid][0] = v0 * wn; swt[wid][1] = v1 * wn;
  }
  __syncthreads();
  if (threadIdx.x == 0) {
    int cnt[NEXP];
#pragma unroll
    for (int e = 0; e < NEXP; ++e) cnt[e] = 0;
#pragma unroll
    for (int tt = 0; tt < 4; ++tt) {
      const int e0 = se[tt][0], e1 = se[tt][1];
      const int r0 = cnt[e0]++; const int r1 = cnt[e1]++;
      tokinfo[blockIdx.x * 4 + tt] = e0 | (e1 << 3) | (r0 << 6) | (r1 << 10);
      ((float2*)tokw)[blockIdx.x * 4 + tt] = make_float2(swt[tt][0], swt[tt][1]);
    }
#pragma unroll
    for (int e = 0; e < NEXP; ++e) bcnt[blockIdx.x * NEXP + e] = cnt[e];
  }
  if (threadIdx.x < NEXP)
    spart[blockIdx.x * NEXP + threadIdx.x] =
        sp[0][threadIdx.x] + sp[1][threadIdx.x] + sp[2][threadIdx.x] + sp[3][threadIdx.x];
}

// ---------------- gate phase B: scan counts -> offsets, ecnt, tile map, aux ----------------
__global__ __launch_bounds__(512) void scan_kernel(
    const int* __restrict__ bcnt, int* __restrict__ boff, int* __restrict__ ecnt,
    const float* __restrict__ spart, float* __restrict__ aux_out,
    int* __restrict__ pad_off, int* __restrict__ tile_map, int* __restrict__ ntiles)
{
  const int w = threadIdx.x >> 6, l = threadIdx.x & 63;  // wave w handles expert w
  int run = 0;
#pragma unroll 4
  for (int c = 0; c < (T_TOK / 4) / 64; ++c) {
    const int b = c * 64 + l;
    const int v = bcnt[b * NEXP + w];
    int sc = v;
#pragma unroll
    for (int off = 1; off < 64; off <<= 1) {
      const int t = __shfl_up(sc, off);
      if (l >= off) sc += t;
    }
    boff[b * NEXP + w] = run + sc - v;
    run += __shfl(sc, 63);
  }
  if (l == 0) ecnt[w] = run;
  float fs = 0.f;
  for (int c = 0; c < (T_TOK / 4) / 64; ++c) fs += spart[(c * 64 + l) * NEXP + w];
#pragma unroll
  for (int off = 32; off > 0; off >>= 1) fs += __shfl_xor(fs, off);
  __shared__ float pis[NEXP];
  __shared__ int cs[NEXP];
  if (l == 0) { pis[w] = fs; cs[w] = run; }
  __syncthreads();
  if (threadIdx.x == 0) {
    float aux = 0.f;
#pragma unroll
    for (int e = 0; e < NEXP; ++e) {
      const float Pi = pis[e] / (float)T_TOK;
      const float ce = (float)cs[e] / (float)(T_TOK * TOPK_);
      aux += Pi * ce * (float)NEXP;
    }
    aux_out[0] = aux * 0.01f;
    int acc = 0, nt = 0;
    for (int e = 0; e < NEXP; ++e) {
      pad_off[e] = acc;
      const int te = (cs[e] + 127) >> 7;
      for (int t = 0; t < te; ++t) {
        tile_map[2 * nt]     = e | ((t * 128) << 4);
        tile_map[2 * nt + 1] = acc + t * 128;
        ++nt;
      }
      acc += te * 128;
    }
    ntiles[0] = nt;
  }
}

// ---------------- gate phase C: scatter tokens into concat + per-expert lists ----------------
__global__ __launch_bounds__(256) void scatter_kernel(
    const int* __restrict__ tokinfo, const float* __restrict__ tokw,
    const int* __restrict__ boff, const int* __restrict__ pad_off,
    int* __restrict__ erows, float* __restrict__ ew,
    int* __restrict__ grows, float* __restrict__ gww)
{
  const int t = blockIdx.x * 256 + threadIdx.x;
  const int info = tokinfo[t];
  const int e0 = info & 7, e1 = (info >> 3) & 7;
  const int r0 = (info >> 6) & 15, r1 = (info >> 10) & 15;
  const int b = t >> 2;
  const float2 wv = ((const float2*)tokw)[t];
  const int p0 = boff[b * NEXP + e0] + r0;
  erows[e0 * T_TOK + p0] = t; ew[e0 * T_TOK + p0] = wv.x;
  const int g0 = pad_off[e0] + p0;
  grows[g0] = t; gww[g0] = wv.x;
  const int p1 = boff[b * NEXP + e1] + r1;
  erows[e1 * T_TOK + p1] = t; ew[e1 * T_TOK + p1] = wv.y;
  const int g1 = pad_off[e1] + p1;
  grows[g1] = t; gww[g1] = wv.y;
}

// ---------------- x fp32 -> bf16 ----------------
__global__ __launch_bounds__(256) void cvt_x_kernel(const float* __restrict__ x,
                                                    __hip_bfloat16* __restrict__ xb)
{
  const int i = blockIdx.x * 256 + threadIdx.x;
  const float4 v = ((const float4*)x)[i];
  union { __hip_bfloat16 h[4]; uint2 u; } o;
  o.h[0] = __float2bfloat16(v.x); o.h[1] = __float2bfloat16(v.y);
  o.h[2] = __float2bfloat16(v.z); o.h[3] = __float2bfloat16(v.w);
  ((uint2*)xb)[i] = o.u;
}

// ---------------- batched transpose+convert: 4096 32x32 tiles per matrix ----------------
struct TD { const float* src; __hip_bfloat16* dst; int N; int nsh; int M; };
struct TB { TD d[27]; };
__global__ __launch_bounds__(256) void tbatch_kernel(TB tb)
{
  const int m = blockIdx.x >> 12;
  const int t = blockIdx.x & 4095;
  const TD td = tb.d[m];
  const int n0 = (t & ((1 << td.nsh) - 1)) << 5;
  const int m0 = (t >> td.nsh) << 5;
  __shared__ float tile[32][33];
  const int tx = threadIdx.x & 31, ty = threadIdx.x >> 5;
#pragma unroll
  for (int i = 0; i < 4; ++i)
    tile[ty + 8 * i][tx] = td.src[(size_t)(m0 + ty + 8 * i) * td.N + n0 + tx];
  __syncthreads();
#pragma unroll
  for (int i = 0; i < 4; ++i)
    td.dst[(size_t)(n0 + ty + 8 * i) * td.M + m0 + tx] = __float2bfloat16(tile[tx][ty + 8 * i]);
}

// ---------------- GEMM1: mid = silu(A@Wg^T)*(A@Wu^T) ----------------
// MODE 0: dense (shared expert, identity rows). MODE 1: per-expert gather (LOW plan).
// MODE 2: grouped over all experts via tile_map (FULL plan).
template <int MODE>
__global__ __launch_bounds__(256, 2) void gemm1_kernel(
    const __hip_bfloat16* __restrict__ xb, const __hip_bfloat16* __restrict__ bgT,
    const __hip_bfloat16* __restrict__ buT, __hip_bfloat16* __restrict__ mid,
    const int* __restrict__ rowlist, const int* __restrict__ cnt_ptr, int row_base,
    const int* __restrict__ tile_map, const int* __restrict__ ntiles)
{
  __shared__ __align__(16) short lA[128 * 32];
  __shared__ __align__(16) short lBg[128 * 32];
  __shared__ __align__(16) short lBu[128 * 32];

  int rows_valid, gb = 0;
  const short* bg = (const short*)bgT;
  const short* bu = (const short*)buT;
  if constexpr (MODE == 2) {
    const int ti = blockIdx.y;
    if (ti >= ntiles[0]) return;
    const int tm = tile_map[2 * ti];
    const int e = tm & 15, rb = tm >> 4;
    gb = tile_map[2 * ti + 1];
    rows_valid = cnt_ptr[e] - rb;
    bg += (size_t)e * CDIM * HDIM;
    bu += (size_t)e * CDIM * HDIM;
  } else {
    const int cnt = (MODE == 1) ? cnt_ptr[0] : T_TOK;
    rows_valid = cnt - row_base;
    if ((int)blockIdx.y * 128 >= rows_valid) return;
  }

  const int tid = threadIdx.x, lane = tid & 63, w = tid >> 6;
  const int wr = w >> 1, wc = w & 1;
  const int rs0 = w * 16 + (lane >> 2);
  const int rs1 = rs0 + 64;
  const int k8 = (lane & 3) * 8;

  int ga0, ga1;
  if constexpr (MODE == 2) {
    ga0 = (rs0 < rows_valid) ? rowlist[gb + rs0] : 0;
    ga1 = (rs1 < rows_valid) ? rowlist[gb + rs1] : 0;
  } else if constexpr (MODE == 1) {
    const int base = row_base + (int)blockIdx.y * 128;
    ga0 = (base + rs0 < cnt_ptr[0]) ? rowlist[base + rs0] : 0;
    ga1 = (base + rs1 < cnt_ptr[0]) ? rowlist[base + rs1] : 0;
  } else {
    ga0 = row_base + (int)blockIdx.y * 128 + rs0;
    ga1 = row_base + (int)blockIdx.y * 128 + rs1;
  }
  const short* sA0 = (const short*)xb + (size_t)ga0 * CDIM + k8;
  const short* sA1 = (const short*)xb + (size_t)ga1 * CDIM + k8;
  const int n0 = blockIdx.x * 128;
  const short* sG0 = bg + (size_t)(n0 + rs0) * CDIM + k8;
  const short* sG1 = bg + (size_t)(n0 + rs1) * CDIM + k8;
  const short* sU0 = bu + (size_t)(n0 + rs0) * CDIM + k8;
  const short* sU1 = bu + (size_t)(n0 + rs1) * CDIM + k8;
  short* dA0 = lA + w * 512;  short* dA1 = dA0 + 2048;
  short* dG0 = lBg + w * 512; short* dG1 = dG0 + 2048;
  short* dU0 = lBu + w * 512; short* dU1 = dU0 + 2048;

  const int aoff = (wr * 64 + (lane & 15)) * 32 + (lane >> 4) * 8;
  const int boff = (wc * 64 + (lane & 15)) * 32 + (lane >> 4) * 8;

  f32x4 accg[4][4], accu[4][4];
#pragma unroll
  for (int i = 0; i < 4; ++i)
#pragma unroll
    for (int j = 0; j < 4; ++j) { accg[i][j] = (f32x4){0.f,0.f,0.f,0.f}; accu[i][j] = (f32x4){0.f,0.f,0.f,0.f}; }

  for (int k0 = 0; k0 < CDIM; k0 += 32) {
    gload16(sA0, dA0); gload16(sA1, dA1);
    gload16(sG0, dG0); gload16(sG1, dG1);
    gload16(sU0, dU0); gload16(sU1, dU1);
    sA0 += 32; sA1 += 32; sG0 += 32; sG1 += 32; sU0 += 32; sU1 += 32;
    __syncthreads();
    short8 af[4], gf[4], uf[4];
#pragma unroll
    for (int i = 0; i < 4; ++i) {
      af[i] = *(const short8*)(lA + aoff + i * 16 * 32);
      gf[i] = *(const short8*)(lBg + boff + i * 16 * 32);
      uf[i] = *(const short8*)(lBu + boff + i * 16 * 32);
    }
#pragma unroll
    for (int mi = 0; mi < 4; ++mi)
#pragma unroll
      for (int ni = 0; ni < 4; ++ni) {
        accg[mi][ni] = __builtin_amdgcn_mfma_f32_16x16x32_bf16(af[mi], gf[ni], accg[mi][ni], 0, 0, 0);
        accu[mi][ni] = __builtin_amdgcn_mfma_f32_16x16x32_bf16(af[mi], uf[ni], accu[mi][ni], 0, 0, 0);
      }
    __syncthreads();
  }

  const int rloc = (MODE == 2) ? 0 : (int)blockIdx.y * 128;
  const int rb0 = rloc + wr * 64;
  const int hb0 = n0 + wc * 64;
  const int rl = (lane >> 4) * 4, cl = lane & 15;
#pragma unroll
  for (int mi = 0; mi < 4; ++mi) {
#pragma unroll
    for (int j = 0; j < 4; ++j) {
      const int r = rb0 + mi * 16 + rl + j;
      const int rv = (MODE == 2) ? (wr * 64 + mi * 16 + rl + j) : r;
      if (rv < rows_valid) {
        __hip_bfloat16* mp = mid + (size_t)(gb + r) * HDIM + hb0 + cl;
#pragma unroll
        for (int ni = 0; ni < 4; ++ni) {
          const float g = accg[mi][ni][j], u = accu[mi][ni][j];
          const float sv = g / (1.f + __expf(-g));
          mp[ni * 16] = __float2bfloat16(sv * u);
        }
      }
    }
  }
}

// ---------------- GEMM2: y (+)= w * (mid @ Wd) ----------------
template <int MODE>
__global__ __launch_bounds__(256, 2) void gemm2_kernel(
    const __hip_bfloat16* __restrict__ mid, const __hip_bfloat16* __restrict__ bdT,
    float* __restrict__ y, const int* __restrict__ rowlist,
    const float* __restrict__ roww, const int* __restrict__ cnt_ptr,
    int row_base, const float* __restrict__ sscale,
    const int* __restrict__ tile_map, const int* __restrict__ ntiles)
{
  __shared__ __align__(16) short lA[128 * 32];
  __shared__ __align__(16) short lB[128 * 32];

  int rows_valid, gb = 0;
  const short* bd = (const short*)bdT;
  if constexpr (MODE == 2) {
    const int ti = blockIdx.y;
    if (ti >= ntiles[0]) return;
    const int tm = tile_map[2 * ti];
    const int e = tm & 15, rb = tm >> 4;
    gb = tile_map[2 * ti + 1];
    rows_valid = cnt_ptr[e] - rb;
    bd += (size_t)e * HDIM * CDIM;
  } else {
    const int cnt = (MODE == 1) ? cnt_ptr[0] : T_TOK;
    rows_valid = cnt - row_base;
    if ((int)blockIdx.y * 128 >= rows_valid) return;
  }

  const int tid = threadIdx.x, lane = tid & 63, w = tid >> 6;
  const int wr = w >> 1, wc = w & 1;
  const int rs0 = w * 16 + (lane >> 2);
  const int rs1 = rs0 + 64;
  const int k8 = (lane & 3) * 8;

  const int arow = (MODE == 2) ? gb : (int)blockIdx.y * 128;
  const short* sA0 = (const short*)mid + (size_t)(arow + rs0) * HDIM + k8;
  const short* sA1 = (const short*)mid + (size_t)(arow + rs1) * HDIM + k8;
  const int n0 = blockIdx.x * 128;
  const short* sB0 = bd + (size_t)(n0 + rs0) * HDIM + k8;
  const short* sB1 = bd + (size_t)(n0 + rs1) * HDIM + k8;
  short* dA0 = lA + w * 512; short* dA1 = dA0 + 2048;
  short* dB0 = lB + w * 512; short* dB1 = dB0 + 2048;

  const int aoff = (wr * 64 + (lane & 15)) * 32 + (lane >> 4) * 8;
  const int boff = (wc * 64 + (lane & 15)) * 32 + (lane >> 4) * 8;

  f32x4 acc[4][4];
#pragma unroll
  for (int i = 0; i < 4; ++i)
#pragma unroll
    for (int j = 0; j < 4; ++j) acc[i][j] = (f32x4){0.f,0.f,0.f,0.f};

  for (int k0 = 0; k0 < HDIM; k0 += 32) {
    gload16(sA0, dA0); gload16(sA1, dA1);
    gload16(sB0, dB0); gload16(sB1, dB1);
    sA0 += 32; sA1 += 32; sB0 += 32; sB1 += 32;
    __syncthreads();
    short8 af[4], bf[4];
#pragma unroll
    for (int i = 0; i < 4; ++i) {
      af[i] = *(const short8*)(lA + aoff + i * 16 * 32);
      bf[i] = *(const short8*)(lB + boff + i * 16 * 32);
    }
#pragma unroll
    for (int mi = 0; mi < 4; ++mi)
#pragma unroll
      for (int ni = 0; ni < 4; ++ni)
        acc[mi][ni] = __builtin_amdgcn_mfma_f32_16x16x32_bf16(af[mi], bf[ni], acc[mi][ni], 0, 0, 0);
    __syncthreads();
  }

  const int cb0 = n0 + wc * 64;
  const int rl = (lane >> 4) * 4, cl = lane & 15;
#pragma unroll
  for (int mi = 0; mi < 4; ++mi) {
#pragma unroll
    for (int j = 0; j < 4; ++j) {
      const int rv = wr * 64 + mi * 16 + rl + j;
      if (rv < rows_valid) {
        if constexpr (MODE == 2) {
          const int tok = rowlist[gb + rv];
          const float wgt = roww[gb + rv];
          float* yp = y + (size_t)tok * CDIM + cb0 + cl;
#pragma unroll
          for (int ni = 0; ni < 4; ++ni) unsafeAtomicAdd(yp + ni * 16, wgt * acc[mi][ni][j]);
        } else if constexpr (MODE == 1) {
          const int lrow = row_base + (int)blockIdx.y * 128 + rv;
          const int tok = rowlist[lrow];
          const float wgt = roww[lrow];
          float* yp = y + (size_t)tok * CDIM + cb0 + cl;
#pragma unroll
          for (int ni = 0; ni < 4; ++ni) unsafeAtomicAdd(yp + ni * 16, wgt * acc[mi][ni][j]);
        } else {
          const float ss = sscale[0];
          const int lrow = row_base + (int)blockIdx.y * 128 + rv;
          float* yp = y + (size_t)lrow * CDIM + cb0 + cl;
#pragma unroll
          for (int ni = 0; ni < 4; ++ni) yp[ni * 16] = ss * acc[mi][ni][j];
        }
      }
    }
  }
}

// ---------------- host ----------------
extern "C" void kernel_launch(void* const* d_in, const int* in_sizes, int n_in,
                              void* d_out, int out_size, void* d_ws, size_t ws_size,
                              hipStream_t stream)
{
  const float* x   = (const float*)d_in[0];
  const float* gw  = (const float*)d_in[1];
  const float* wg  = (const float*)d_in[2];
  const float* wu  = (const float*)d_in[3];
  const float* wd  = (const float*)d_in[4];
  const float* swg = (const float*)d_in[5];
  const float* swu = (const float*)d_in[6];
  const float* swd = (const float*)d_in[7];
  const float* ssc = (const float*)d_in[8];
  float* y = (float*)d_out;

  auto al = [](size_t v) { return (v + 255) & ~(size_t)255; };
  char* ws = (char*)d_ws;
  size_t off = 0;
  __hip_bfloat16* xb = (__hip_bfloat16*)(ws + off); off += al((size_t)T_TOK * CDIM * 2);
  int*   tokinfo = (int*)(ws + off);   off += al((size_t)T_TOK * 4);
  float* tokw    = (float*)(ws + off); off += al((size_t)T_TOK * 8);
  int*   bcnt    = (int*)(ws + off);   off += al((size_t)(T_TOK / 4) * NEXP * 4);
  int*   boffb   = (int*)(ws + off);   off += al((size_t)(T_TOK / 4) * NEXP * 4);
  float* spart   = (float*)(ws + off); off += al((size_t)(T_TOK / 4) * NEXP * 4);
  int*   ecnt    = (int*)(ws + off);   off += 256;
  int*   pad_off = (int*)(ws + off);   off += 256;
  int*   ntiles  = (int*)(ws + off);   off += 256;
  int*   tile_map= (int*)(ws + off);   off += al((size_t)MAXTILES * 2 * 4);
  int*   erows   = (int*)(ws + off);   off += al((size_t)NEXP * T_TOK * 4);
  float* ew      = (float*)(ws + off); off += al((size_t)NEXP * T_TOK * 4);
  int*   grows   = (int*)(ws + off);   off += al((size_t)MAXROWS * 4);
  float* gww     = (float*)(ws + off); off += al((size_t)MAXROWS * 4);

  const size_t WMAT = (size_t)CDIM * HDIM;  // 4M elems per matrix
  const size_t full_need = off + 27 * WMAT * 2 + (size_t)MAXROWS * HDIM * 2;

  // common prologue
  gate_kernel<<<T_TOK / 4, 256, 0, stream>>>(x, gw, tokinfo, tokw, bcnt, spart);
  scan_kernel<<<1, 512, 0, stream>>>(bcnt, boffb, ecnt, spart, y + (size_t)T_TOK * CDIM,
                                     pad_off, tile_map, ntiles);
  scatter_kernel<<<T_TOK / 256, 256, 0, stream>>>(tokinfo, tokw, boffb, pad_off,
                                                  erows, ew, grows, gww);
  cvt_x_kernel<<<T_TOK * CDIM / 4 / 256, 256, 0, stream>>>(x, xb);

  if (ws_size >= full_need) {
    // ---------- FULL plan: one batched cvt + grouped GEMMs ----------
    __hip_bfloat16* wAll = (__hip_bfloat16*)(ws + off); off += 27 * WMAT * 2;
    __hip_bfloat16* mid  = (__hip_bfloat16*)(ws + off);
    __hip_bfloat16* wgA = wAll;
    __hip_bfloat16* wuA = wAll + 8 * WMAT;
    __hip_bfloat16* wdA = wAll + 16 * WMAT;
    __hip_bfloat16* sgT = wAll + 24 * WMAT;
    __hip_bfloat16* suT = wAll + 25 * WMAT;
    __hip_bfloat16* sdT = wAll + 26 * WMAT;

    TB tb;
    for (int e = 0; e < 8; ++e) {
      tb.d[e]      = TD{wg + e * WMAT, wgA + e * WMAT, HDIM, 7, CDIM};
      tb.d[8 + e]  = TD{wu + e * WMAT, wuA + e * WMAT, HDIM, 7, CDIM};
      tb.d[16 + e] = TD{wd + e * WMAT, wdA + e * WMAT, CDIM, 5, HDIM};
    }
    tb.d[24] = TD{swg, sgT, HDIM, 7, CDIM};
    tb.d[25] = TD{swu, suT, HDIM, 7, CDIM};
    tb.d[26] = TD{swd, sdT, CDIM, 5, HDIM};
    tbatch_kernel<<<27 * 4096, 256, 0, stream>>>(tb);

    // dense (shared) first: plain stores establish y
    gemm1_kernel<0><<<dim3(HDIM / 128, T_TOK / 128), 256, 0, stream>>>(
        xb, sgT, suT, mid, nullptr, nullptr, 0, nullptr, nullptr);
    gemm2_kernel<0><<<dim3(CDIM / 128, T_TOK / 128), 256, 0, stream>>>(
        mid, sdT, y, nullptr, nullptr, nullptr, 0, ssc, nullptr, nullptr);
    // grouped routed (mid reused after dense gemm2 completed)
    gemm1_kernel<2><<<dim3(HDIM / 128, MAXTILES - 1), 256, 0, stream>>>(
        xb, wgA, wuA, mid, grows, ecnt, 0, tile_map, ntiles);
    gemm2_kernel<2><<<dim3(CDIM / 128, MAXTILES - 1), 256, 0, stream>>>(
        mid, wdA, y, grows, gww, ecnt, 0, nullptr, tile_map, ntiles);
  } else {
    // ---------- LOW plan: rotating 3-buffer weights, per-expert GEMMs ----------
    __hip_bfloat16* wgT = (__hip_bfloat16*)(ws + off); off += WMAT * 2;
    __hip_bfloat16* wuT = (__hip_bfloat16*)(ws + off); off += WMAT * 2;
    __hip_bfloat16* wdT = (__hip_bfloat16*)(ws + off); off += WMAT * 2;
    off = al(off);
    __hip_bfloat16* mid = (__hip_bfloat16*)(ws + off);
    const size_t mid_avail = (ws_size > off) ? (ws_size - off) : 0;
    int RC = 1024;
    if      (mid_avail >= (size_t)8192 * HDIM * 2) RC = 8192;
    else if (mid_avail >= (size_t)4096 * HDIM * 2) RC = 4096;
    else if (mid_avail >= (size_t)2048 * HDIM * 2) RC = 2048;

    TB tb;
    tb.d[0] = TD{swg, wgT, HDIM, 7, CDIM};
    tb.d[1] = TD{swu, wuT, HDIM, 7, CDIM};
    tb.d[2] = TD{swd, wdT, CDIM, 5, HDIM};
    tbatch_kernel<<<3 * 4096, 256, 0, stream>>>(tb);
    for (int rb = 0; rb < T_TOK; rb += RC) {
      gemm1_kernel<0><<<dim3(HDIM / 128, RC / 128), 256, 0, stream>>>(
          xb, wgT, wuT, mid, nullptr, nullptr, rb, nullptr, nullptr);
      gemm2_kernel<0><<<dim3(CDIM / 128, RC / 128), 256, 0, stream>>>(
          mid, wdT, y, nullptr, nullptr, nullptr, rb, ssc, nullptr, nullptr);
    }
    for (int e = 0; e < NEXP; ++e) {
      TB te;
      te.d[0] = TD{wg + e * WMAT, wgT, HDIM, 7, CDIM};
      te.d[1] = TD{wu + e * WMAT, wuT, HDIM, 7, CDIM};
      te.d[2] = TD{wd + e * WMAT, wdT, CDIM, 5, HDIM};
      tbatch_kernel<<<3 * 4096, 256, 0, stream>>>(te);
      for (int rb = 0; rb < T_TOK; rb += RC) {
        gemm1_kernel<1><<<dim3(HDIM / 128, RC / 128), 256, 0, stream>>>(
            xb, wgT, wuT, mid, erows + (size_t)e * T_TOK, ecnt + e, rb, nullptr, nullptr);
        gemm2_kernel<1><<<dim3(CDIM / 128, RC / 128), 256, 0, stream>>>(
            mid, wdT, y, erows + (size_t)e * T_TOK, ew + (size_t)e * T_TOK, ecnt + e, rb,
            nullptr, nullptr, nullptr);
      }
    }
  }
}